// Round 11
// baseline (76.777 us; speedup 1.0000x reference)
//
#include <hip/hip_runtime.h>

#define N_NODES 50000
#define N_EDGES 600000
#define DIM 128
#define NB 782                 // 64-node buckets (= gather blocks)
#define NJ 391                 // gemm/scatter blocks; 2 tiles or 1536 edges each
#define EPB 1536               // edges per partition block: 391*1536 = 600576
#define GCAP 2048              // gather LDS sort capacity (mean 767, sd 28)

typedef short bf16x8 __attribute__((ext_vector_type(8)));
typedef float f32x4 __attribute__((ext_vector_type(4)));

__device__ __forceinline__ float bf2f(unsigned short u) {
    union { unsigned int i; float f; } x; x.i = ((unsigned int)u) << 16; return x.f;
}
__device__ __forceinline__ float bflo(unsigned int u) {
    union { unsigned int i; float f; } x; x.i = u << 16; return x.f;
}
__device__ __forceinline__ float bfhi(unsigned int u) {
    union { unsigned int i; float f; } x; x.i = u & 0xFFFF0000u; return x.f;
}
__device__ __forceinline__ unsigned short f2bf(float f) {
    union { float f; unsigned int i; } x; x.f = f;
    unsigned int r = x.i + 0x7FFFu + ((x.i >> 16) & 1u);   // RNE
    return (unsigned short)(r >> 16);
}

// ---------------- MFMA GEMM: 2 node-tiles/block sharing one W staging ----------------
__global__ __launch_bounds__(512) void gemm_kernel(const float* __restrict__ x,
                                                   const float* __restrict__ W,
                                                   unsigned short* __restrict__ h,
                                                   const int* __restrict__ rows,
                                                   unsigned short* __restrict__ Hm16,
                                                   int* __restrict__ done) {
    __shared__ unsigned char Wl[128 * 256];   // bf16[128 dims][128 k], swizzled
    __shared__ int cntL[NB];
    const int tid = threadIdx.x;

    if (Hm16) {
        for (int i = tid; i < NB; i += 512) cntL[i] = 0;
        if (blockIdx.x == 0 && tid == 0) *done = 0;    // reset last-block counter
    }

    // ---- stage W -> LDS bf16 (swizzled): 4096 float4 chunks, 8 per thread
#pragma unroll
    for (int i = 0; i < 8; ++i) {
        int c  = tid + i * 512;
        int od = c >> 5;
        int kg = c & 31;
        float4 w = *((const float4*)(W + od * DIM) + kg);
        unsigned int lo = (unsigned int)f2bf(w.x) | ((unsigned int)f2bf(w.y) << 16);
        unsigned int hi = (unsigned int)f2bf(w.z) | ((unsigned int)f2bf(w.w) << 16);
        int byte = od * 256 + ((kg * 8) ^ ((od & 7) << 4));
        *reinterpret_cast<uint2*>(Wl + byte) = make_uint2(lo, hi);
    }

    // ---- this wave's tile + node (node = lane&15, k-slot q = lane>>4)
    const int lane = tid & 63;
    const int w8   = tid >> 6;          // wave 0..7
    const int wv   = w8 & 3;            // wave-in-tile
    const int t    = blockIdx.x * 2 + (w8 >> 2);   // tile 0..781
    const int q    = lane >> 4;
    const int node = t * 64 + wv * 16 + (lane & 15);
    const int ncl  = node < N_NODES ? node : N_NODES - 1;

    bf16x8 xb[4];
#pragma unroll
    for (int s = 0; s < 4; ++s) {
        const float* xp = x + (size_t)ncl * DIM + s * 32 + q * 8;
        float4 x0 = *(const float4*)(xp);
        float4 x1 = *(const float4*)(xp + 4);
        bf16x8 v;
        v[0] = (short)f2bf(x0.x); v[1] = (short)f2bf(x0.y);
        v[2] = (short)f2bf(x0.z); v[3] = (short)f2bf(x0.w);
        v[4] = (short)f2bf(x1.x); v[5] = (short)f2bf(x1.y);
        v[6] = (short)f2bf(x1.z); v[7] = (short)f2bf(x1.w);
        xb[s] = v;
    }

    __syncthreads();   // cntL zeroed + W staged

    // ---- fused histogram: LDS atomics only (1536 edges/block)
    if (Hm16) {
        int ebase = blockIdx.x * EPB;
#pragma unroll
        for (int i = 0; i < 3; ++i) {
            int e = ebase + tid + i * 512;
            if (e < N_EDGES) atomicAdd(&cntL[rows[e] >> 6], 1);
        }
    }

    // ---- 8 dim-tiles x 4 k-steps of mfma_f32_16x16x32_bf16
#pragma unroll
    for (int dt = 0; dt < 8; ++dt) {
        f32x4 acc = {0.f, 0.f, 0.f, 0.f};
        const int od = dt * 16 + (lane & 15);
#pragma unroll
        for (int s = 0; s < 4; ++s) {
            int byte = od * 256 + ((s * 64 + q * 16) ^ ((od & 7) << 4));
            bf16x8 a = *reinterpret_cast<const bf16x8*>(Wl + byte);
            acc = __builtin_amdgcn_mfma_f32_16x16x32_bf16(a, xb[s], acc, 0, 0, 0);
        }
        if (node < N_NODES) {
            unsigned int lo = (unsigned int)f2bf(acc[0]) | ((unsigned int)f2bf(acc[1]) << 16);
            unsigned int hi = (unsigned int)f2bf(acc[2]) | ((unsigned int)f2bf(acc[3]) << 16);
            *reinterpret_cast<uint2*>(h + (size_t)node * DIM + dt * 16 + q * 4) = make_uint2(lo, hi);
        }
    }

    if (Hm16) {
        __syncthreads();
        unsigned short* Hrow = Hm16 + (size_t)blockIdx.x * NB;
        for (int i = tid; i < NB; i += 512) Hrow[i] = (unsigned short)cntL[i];
    }
}

// ---------------- scanAB: coalesced per-bucket scan along j + last-block scanB ----------------
__global__ __launch_bounds__(512) void scanAB_kernel(unsigned short* __restrict__ Hm16,
                                                     int* __restrict__ tot,
                                                     int* __restrict__ boff,
                                                     int* __restrict__ done) {
    __shared__ int part[8 * 64];
    __shared__ int lastFlag;
    int tid = threadIdx.x, g = blockIdx.x;
    int w = tid >> 6, lane = tid & 63;
    int bucket = g * 64 + lane;
    bool bv = bucket < NB;
    int j0 = w * 49;
    int j1 = j0 + 49; if (j1 > NJ) j1 = NJ;

    // pass 1: per-(wave,bucket) partial sums
    int ps = 0;
    if (bv) for (int j = j0; j < j1; ++j) ps += Hm16[(size_t)j * NB + bucket];
    part[w * 64 + lane] = ps;
    __syncthreads();
    int base = 0, total = 0;
#pragma unroll
    for (int ww = 0; ww < 8; ++ww) {
        int p = part[ww * 64 + lane];
        if (ww < w) base += p;
        total += p;
    }
    if (w == 0 && bv) tot[bucket] = total;

    // pass 2: write exclusive prefix back (u16)
    if (bv) {
        int carry = base;
        for (int j = j0; j < j1; ++j) {
            size_t idx = (size_t)j * NB + bucket;
            int v = Hm16[idx];
            Hm16[idx] = (unsigned short)carry;
            carry += v;
        }
    }
    __syncthreads();
    if (tid == 0) {
        __threadfence();
        int old = atomicAdd(done, 1);
        lastFlag = (old == (int)gridDim.x - 1) ? 1 : 0;
    }
    __syncthreads();
    if (lastFlag) {
        __threadfence();   // acquire other blocks' tot writes
        if (tid < 64) {
            int carry = 0;
            for (int ch = 0; ch < 13; ++ch) {
                int i = ch * 64 + tid;
                int v = (i < NB) ? tot[i] : 0;
                int incl = v;
#pragma unroll
                for (int d = 1; d < 64; d <<= 1) {
                    int t = __shfl_up(incl, d);
                    if (tid >= d) incl += t;
                }
                if (i < NB) boff[i] = carry + incl - v;
                carry += __shfl(incl, 63);
            }
            if (tid == 0) { boff[NB] = N_EDGES; *done = 0; }
        }
    }
}

// ---------------- scatter: deterministic bucket partition, LDS cursors ----------------
__global__ __launch_bounds__(512) void scatter_kernel(const int* __restrict__ rows,
                                                      const int* __restrict__ cols,
                                                      const float* __restrict__ vals,
                                                      const unsigned short* __restrict__ Hm16,
                                                      const int* __restrict__ boff,
                                                      int2* __restrict__ erec) {
    __shared__ int cl[NB];
    int tid = threadIdx.x, j = blockIdx.x;
    const unsigned short* Hrow = Hm16 + (size_t)j * NB;
    for (int i = tid; i < NB; i += 512) cl[i] = boff[i] + (int)Hrow[i];
    __syncthreads();
    int ebase = j * EPB;
#pragma unroll
    for (int i = 0; i < 3; ++i) {
        int e = ebase + tid + i * 512;
        if (e < N_EDGES) {
            int r = rows[e];
            int slot = atomicAdd(&cl[r >> 6], 1);
            int2 rec;
            rec.x = cols[e] | ((r & 63) << 16);
            rec.y = __float_as_int(vals[e]);
            erec[slot] = rec;
        }
    }
}

// ---------------- gather: LDS counting sort + QUARTER-WAVE per node ----------------
// 512 threads, 8 waves, 8 nodes/wave. One full wave per node, but split into
// 4 QUARTERS: 16 lanes x uint4 (16B) = 256B = one full h-row, so ONE wave-load
// instruction fetches 4 edges' rows. Quarter k walks the node's edge stream at
// stride 4 (deg~12 -> 3 records/quarter); 2-deep unroll -> up to 8 edges in
// flight/wave. Combine via shfl_xor(16)+shfl_xor(32); lanes 0-15 store 32B.
__global__ __launch_bounds__(512) void gather_kernel(const unsigned short* __restrict__ h,
                                                     const int2* __restrict__ erec,
                                                     const int* __restrict__ boff,
                                                     float* __restrict__ out) {
    __shared__ int2 srt[GCAP];            // 16 KB sorted records
    __shared__ int hist[64];
    __shared__ int cursor[64];
    __shared__ int starts[65];
    int tid = threadIdx.x, b = blockIdx.x;
    int beg = boff[b], end = boff[b + 1];
    int cnt = end - beg;
    int w = tid >> 6, lane = tid & 63;
    int pos = lane & 15;                  // dim group: dims pos*8 .. pos*8+7
    int quarter = lane >> 4;

    if (tid < 64) hist[tid] = 0;
    __syncthreads();

    if (cnt <= GCAP) {
        // ---- phase 1: stage to registers + 64-bin histogram
        int2 rec[4];
        int  rr[4];
#pragma unroll
        for (int k = 0; k < 4; ++k) {
            int i = tid + k * 512;
            if (i < cnt) {
                rec[k] = erec[beg + i];
                rr[k] = (rec[k].x >> 16) & 63;
                atomicAdd(&hist[rr[k]], 1);
            }
        }
        __syncthreads();
        // ---- phase 2: exclusive scan of the 64 bins (wave 0)
        if (tid < 64) {
            int v = hist[tid], incl = v;
#pragma unroll
            for (int d = 1; d < 64; d <<= 1) {
                int t = __shfl_up(incl, d);
                if (tid >= d) incl += t;
            }
            starts[tid] = incl - v;
            cursor[tid] = incl - v;
            if (tid == 63) starts[64] = incl;
        }
        __syncthreads();
        // ---- phase 3: place into sorted LDS order
#pragma unroll
        for (int k = 0; k < 4; ++k) {
            int i = tid + k * 512;
            if (i < cnt) {
                int p2 = atomicAdd(&cursor[rr[k]], 1);
                srt[p2] = rec[k];
            }
        }
        __syncthreads();
        // ---- phase 4: quarter-wave streams, 2-deep unroll
        for (int t0 = 0; t0 < 8; ++t0) {
            int t = w * 8 + t0;
            int node = b * 64 + t;
            int s0 = starts[t], s1 = starts[t + 1];
            float a0 = 0.f, a1 = 0.f, a2 = 0.f, a3 = 0.f;
            float a4 = 0.f, a5 = 0.f, a6 = 0.f, a7 = 0.f;
            int i = s0 + quarter;
            for (; i + 4 < s1; i += 8) {
                int2 r0 = srt[i], r1 = srt[i + 4];
                uint4 u0 = *((const uint4*)(h + (size_t)(r0.x & 0xFFFF) * DIM) + pos);
                uint4 u1 = *((const uint4*)(h + (size_t)(r1.x & 0xFFFF) * DIM) + pos);
                float v0 = __int_as_float(r0.y), v1 = __int_as_float(r1.y);
                a0 += v0 * bflo(u0.x) + v1 * bflo(u1.x);
                a1 += v0 * bfhi(u0.x) + v1 * bfhi(u1.x);
                a2 += v0 * bflo(u0.y) + v1 * bflo(u1.y);
                a3 += v0 * bfhi(u0.y) + v1 * bfhi(u1.y);
                a4 += v0 * bflo(u0.z) + v1 * bflo(u1.z);
                a5 += v0 * bfhi(u0.z) + v1 * bfhi(u1.z);
                a6 += v0 * bflo(u0.w) + v1 * bflo(u1.w);
                a7 += v0 * bfhi(u0.w) + v1 * bfhi(u1.w);
            }
            for (; i < s1; i += 4) {
                int2 r0 = srt[i];
                uint4 u0 = *((const uint4*)(h + (size_t)(r0.x & 0xFFFF) * DIM) + pos);
                float v0 = __int_as_float(r0.y);
                a0 += v0 * bflo(u0.x);
                a1 += v0 * bfhi(u0.x);
                a2 += v0 * bflo(u0.y);
                a3 += v0 * bfhi(u0.y);
                a4 += v0 * bflo(u0.z);
                a5 += v0 * bfhi(u0.z);
                a6 += v0 * bflo(u0.w);
                a7 += v0 * bfhi(u0.w);
            }
            // combine the 4 quarters
            a0 += __shfl_xor(a0, 16); a1 += __shfl_xor(a1, 16);
            a2 += __shfl_xor(a2, 16); a3 += __shfl_xor(a3, 16);
            a4 += __shfl_xor(a4, 16); a5 += __shfl_xor(a5, 16);
            a6 += __shfl_xor(a6, 16); a7 += __shfl_xor(a7, 16);
            a0 += __shfl_xor(a0, 32); a1 += __shfl_xor(a1, 32);
            a2 += __shfl_xor(a2, 32); a3 += __shfl_xor(a3, 32);
            a4 += __shfl_xor(a4, 32); a5 += __shfl_xor(a5, 32);
            a6 += __shfl_xor(a6, 32); a7 += __shfl_xor(a7, 32);
            if (quarter == 0 && node < N_NODES) {
                float4 o0, o1;
                o0.x = fmaxf(a0, 0.f); o0.y = fmaxf(a1, 0.f);
                o0.z = fmaxf(a2, 0.f); o0.w = fmaxf(a3, 0.f);
                o1.x = fmaxf(a4, 0.f); o1.y = fmaxf(a5, 0.f);
                o1.z = fmaxf(a6, 0.f); o1.w = fmaxf(a7, 0.f);
                float* op = &out[(size_t)node * DIM + pos * 8];
                *reinterpret_cast<float4*>(op) = o0;
                *reinterpret_cast<float4*>(op + 4) = o1;
            }
        }
    } else {
        // ---- oversize-bucket fallback (statistically unreachable, kept for correctness)
        for (int t0 = 0; t0 < 8; ++t0) {
            int t = w * 8 + t0;
            int node = b * 64 + t;
            float a0 = 0.f, a1 = 0.f, a2 = 0.f, a3 = 0.f;
            float a4 = 0.f, a5 = 0.f, a6 = 0.f, a7 = 0.f;
            for (int i = quarter; i < cnt; i += 4) {
                int2 r = erec[beg + i];
                if (((r.x >> 16) & 63) == t) {
                    uint4 u0 = *((const uint4*)(h + (size_t)(r.x & 0xFFFF) * DIM) + pos);
                    float v = __int_as_float(r.y);
                    a0 += v * bflo(u0.x);
                    a1 += v * bfhi(u0.x);
                    a2 += v * bflo(u0.y);
                    a3 += v * bfhi(u0.y);
                    a4 += v * bflo(u0.z);
                    a5 += v * bfhi(u0.z);
                    a6 += v * bflo(u0.w);
                    a7 += v * bfhi(u0.w);
                }
            }
            a0 += __shfl_xor(a0, 16); a1 += __shfl_xor(a1, 16);
            a2 += __shfl_xor(a2, 16); a3 += __shfl_xor(a3, 16);
            a4 += __shfl_xor(a4, 16); a5 += __shfl_xor(a5, 16);
            a6 += __shfl_xor(a6, 16); a7 += __shfl_xor(a7, 16);
            a0 += __shfl_xor(a0, 32); a1 += __shfl_xor(a1, 32);
            a2 += __shfl_xor(a2, 32); a3 += __shfl_xor(a3, 32);
            a4 += __shfl_xor(a4, 32); a5 += __shfl_xor(a5, 32);
            a6 += __shfl_xor(a6, 32); a7 += __shfl_xor(a7, 32);
            if (quarter == 0 && node < N_NODES) {
                float4 o0, o1;
                o0.x = fmaxf(a0, 0.f); o0.y = fmaxf(a1, 0.f);
                o0.z = fmaxf(a2, 0.f); o0.w = fmaxf(a3, 0.f);
                o1.x = fmaxf(a4, 0.f); o1.y = fmaxf(a5, 0.f);
                o1.z = fmaxf(a6, 0.f); o1.w = fmaxf(a7, 0.f);
                float* op = &out[(size_t)node * DIM + pos * 8];
                *reinterpret_cast<float4*>(op) = o0;
                *reinterpret_cast<float4*>(op + 4) = o1;
            }
        }
    }
}

// ---------------- fallback: atomic scatter over bf16 h ----------------
__global__ __launch_bounds__(256) void edge_kernel(const unsigned short* __restrict__ h,
                                                   const float* __restrict__ vals,
                                                   const int* __restrict__ rows,
                                                   const int* __restrict__ cols,
                                                   float* __restrict__ out) {
    long long gid = (long long)blockIdx.x * 256 + threadIdx.x;
    int e    = (int)(gid >> 5);
    int lane = (int)(gid & 31);
    if (e >= N_EDGES) return;
    int r = rows[e];
    int c = cols[e];
    float v = vals[e];
    ushort4 hv = *((const ushort4*)(h + (size_t)c * DIM) + lane);
    float* op = &out[(size_t)r * DIM + lane * 4];
    atomicAdd(op + 0, v * bf2f(hv.x));
    atomicAdd(op + 1, v * bf2f(hv.y));
    atomicAdd(op + 2, v * bf2f(hv.z));
    atomicAdd(op + 3, v * bf2f(hv.w));
}

__global__ __launch_bounds__(256) void relu_kernel(float* __restrict__ out) {
    int i = blockIdx.x * 256 + threadIdx.x;
    float4* p = reinterpret_cast<float4*>(out) + i;
    float4 v = *p;
    v.x = fmaxf(v.x, 0.f);
    v.y = fmaxf(v.y, 0.f);
    v.z = fmaxf(v.z, 0.f);
    v.w = fmaxf(v.w, 0.f);
    *p = v;
}

extern "C" void kernel_launch(void* const* d_in, const int* in_sizes, int n_in,
                              void* d_out, int out_size, void* d_ws, size_t ws_size,
                              hipStream_t stream) {
    const float* x    = (const float*)d_in[0];
    const float* W    = (const float*)d_in[1];
    const float* vals = (const float*)d_in[2];
    const int*   rows = (const int*)d_in[3];
    const int*   cols = (const int*)d_in[4];
    float* out = (float*)d_out;

    // ---- workspace layout ----
    unsigned short* h = (unsigned short*)d_ws;                    // 12.8 MB bf16
    int2* erec = (int2*)(h + (size_t)N_NODES * DIM);              // 4.8 MB
    unsigned short* Hm16 = (unsigned short*)(erec + N_EDGES);     // 391*782*2 B
    int*  tot  = (int*)(Hm16 + (size_t)NJ * NB);                  // 782 ints
    int*  boff = tot + NB;                                        // 783 ints
    int*  done = boff + (NB + 1);                                 // 1 int
    size_t need = (size_t)((char*)(done + 1) - (char*)d_ws);

    if (ws_size >= need) {
        gemm_kernel<<<NJ, 512, 0, stream>>>(x, W, h, rows, Hm16, done);
        scanAB_kernel<<<13, 512, 0, stream>>>(Hm16, tot, boff, done);
        scatter_kernel<<<NJ, 512, 0, stream>>>(rows, cols, vals, Hm16, boff, erec);
        gather_kernel<<<NB, 512, 0, stream>>>(h, erec, boff, out);
    } else {
        // fallback: atomic scatter path (needs only h)
        gemm_kernel<<<NJ, 512, 0, stream>>>(x, W, h, nullptr, nullptr, nullptr);
        hipMemsetAsync(d_out, 0, (size_t)N_NODES * DIM * sizeof(float), stream);
        edge_kernel<<<(N_EDGES * 32) / 256, 256, 0, stream>>>(h, vals, rows, cols, out);
        relu_kernel<<<(N_NODES * DIM / 4) / 256, 256, 0, stream>>>(out);
    }
}